// Round 14
// baseline (99.898 us; speedup 1.0000x reference)
//
#include <hip/hip_runtime.h>
#include <math.h>

#define HH 96
#define WW 96
#define PP 9216   // H*W
#define CCH 256
#define BB 4
#define CH 32

typedef unsigned short u16;
typedef short bf16x8 __attribute__((ext_vector_type(8)));
typedef float f32x4 __attribute__((ext_vector_type(4)));

__device__ __forceinline__ float bf2f(unsigned s) { return __uint_as_float(s << 16); }
__device__ __forceinline__ u16 f2bf(float f) {
  unsigned u = __float_as_uint(f);
  return (u16)((u + 0x7fffu + ((u >> 16) & 1u)) >> 16);
}

typedef __attribute__((address_space(1))) const unsigned int GUI;
typedef __attribute__((address_space(3))) unsigned int LUI;
__device__ __forceinline__ void gload16(const void* g, void* l) {
  __builtin_amdgcn_global_load_lds((GUI*)g, (LUI*)l, 16, 0, 0);
}

// ---------------------------------------------------------------------------
// wcvt: W -> bf16 in per-lane FRAGMENT order (unchanged from R8-R13).
// go = ((((kk*2+ks)*4+w4)*4+i)*64+l)*8 holds row=w4*64+i*16+(l&15),
// c = kk*64 + (ks*4+(l>>4))*8 .. +7.
// ---------------------------------------------------------------------------
__global__ __launch_bounds__(256)
void wcvt(const float* __restrict__ wq, const float* __restrict__ wo,
          u16* __restrict__ Wbf) {
  int gidx = blockIdx.x * 256 + threadIdx.x;   // 0..16383
  int mat = gidx >> 13;
  int gi = gidx & 8191;
  int l = gi & 63;
  int i = (gi >> 6) & 3;
  int w = (gi >> 8) & 3;
  int ks = (gi >> 10) & 1;
  int kk = (gi >> 11) & 3;
  const float* W = mat ? wo : wq;
  int row = w * 64 + i * 16 + (l & 15);
  int c0 = kk * 64 + (ks * 4 + (l >> 4)) * 8;
  const float* s = W + (size_t)row * CCH + c0;
  float4 a = *(const float4*)s;
  float4 b = *(const float4*)(s + 4);
  uint4 u;
  u.x = (unsigned)f2bf(a.x) | ((unsigned)f2bf(a.y) << 16);
  u.y = (unsigned)f2bf(a.z) | ((unsigned)f2bf(a.w) << 16);
  u.z = (unsigned)f2bf(b.x) | ((unsigned)f2bf(b.y) << 16);
  u.w = (unsigned)f2bf(b.z) | ((unsigned)f2bf(b.w) << 16);
  *(uint4*)(Wbf + (size_t)gidx * 8) = u;
}

// ---------------------------------------------------------------------------
// Fused projection GEMM v8 — DENSE-GRANULE staging. p-tile = 256 px so every
// gload16 instruction reads one contiguous 1 KB c-row (64 lanes x 16 B).
// 1024 thr / 16 waves; K in 8 eighths of 32c:
//   [barrier A: stage(e) landed + Xb WAR] -> trans(e): fA[32c][256p] f32 ->
//   Xb[256p][32c] bf16 (b128 at bank floor) -> [barrier B] ->
//   stage(e+1) (lands under MFMA) -> 16 MFMA/wave (W from L2, frag order).
// LDS 48 KB; acc[16] ~64 VGPR -> 2 blocks (32 waves) resident.
// ---------------------------------------------------------------------------
#define BM 256
__global__ __launch_bounds__(1024)
void gemm_qkvf(const float* __restrict__ qin, const float* __restrict__ kin,
               const float* __restrict__ vin, const u16* __restrict__ Wbf,
               u16* __restrict__ Xcl) {
  __shared__ float fA[32 * 256];   // 32 KB: [c_local][p]
  __shared__ u16 Xb[256 * 32];     // 16 KB: [p][c], rows 64 B
  const int t = threadIdx.x;
  const int w = t >> 6, l = t & 63;
  const int lr = l & 15, lg = l >> 4;
  const int pblk = blockIdx.x * BM;
  const int z = blockIdx.z;
  const int b = z & 3, which = z >> 2;
  const float* Xf = ((which == 0) ? qin : (which == 1) ? kin : vin) + (size_t)b * CCH * PP;
  u16* Y = Xcl + (size_t)z * ((size_t)PP * CCH);

  // stage eighth e: wave w loads c-rows {2w, 2w+1}; each gload16 = 1 KB dense.
  auto stage = [&](int e) {
#pragma unroll
    for (int j = 0; j < 2; j++) {
      int cl = 2 * w + j;
      gload16(Xf + (size_t)(e * 32 + cl) * PP + pblk + l * 4,
              (void*)&fA[cl * 256]);
    }
  };

  f32x4 acc[16];
#pragma unroll
  for (int pf = 0; pf < 16; pf++) acc[pf] = (f32x4){0.f, 0.f, 0.f, 0.f};

  stage(0);
#pragma unroll
  for (int e = 0; e < 8; e++) {
    __syncthreads();   // A: all waves' stage(e) landed; MFMA(e-1) Xb reads done
    // trans: lane (lr,lg): p = w*16+lr, c-octet lg*8..+7 -> one b128 write
    {
      int p = w * 16 + lr;
      unsigned wds[4];
#pragma unroll
      for (int j = 0; j < 4; j++) {
        float e0 = fA[(lg * 8 + 2 * j) * 256 + p];
        float e1 = fA[(lg * 8 + 2 * j + 1) * 256 + p];
        wds[j] = (unsigned)f2bf(e0) | ((unsigned)f2bf(e1) << 16);
      }
      *(uint4*)(&Xb[p * 32 + lg * 8]) = make_uint4(wds[0], wds[1], wds[2], wds[3]);
    }
    __syncthreads();   // B: Xb ready; fA free for overwrite
    if (e < 7) stage(e + 1);   // lands during MFMA below
    // W fragment for this eighth (L2, fragment order; 16-wave re-index)
    size_t go = ((((size_t)e * 4 + (w >> 2)) * 4 + (w & 3)) * 64 + l) * 8;
    bf16x8 wf = *(const bf16x8*)(Wbf + go);
#pragma unroll
    for (int pf = 0; pf < 16; pf++) {
      bf16x8 xf = *(const bf16x8*)&Xb[(pf * 16 + lr) * 32 + lg * 8];
      acc[pf] = __builtin_amdgcn_mfma_f32_16x16x32_bf16(wf, xf, acc[pf], 0, 0, 0);
    }
  }

  // epilogue: D[o][p], o = w*16 + lg*4 + j, p = pblk + pf*16 + lr -> bf16 CL
#pragma unroll
  for (int pf = 0; pf < 16; pf++) {
    int o = w * 16 + lg * 4;
    int p = pblk + pf * 16 + lr;
    f32x4 a = acc[pf];
    uint2 u;
    u.x = (unsigned)f2bf(a[0]) | ((unsigned)f2bf(a[1]) << 16);
    u.y = (unsigned)f2bf(a[2]) | ((unsigned)f2bf(a[3]) << 16);
    *(uint2*)(Y + (size_t)p * CCH + o) = u;
  }
}

// ---------------------------------------------------------------------------
// Out-projection GEMM (unchanged from R13).
// ---------------------------------------------------------------------------
__global__ __launch_bounds__(256)
void gemm_out_m(const u16* __restrict__ Xbuf, const u16* __restrict__ Wbf,
                const float* __restrict__ bias, float* __restrict__ outY) {
  __shared__ u16 Xl[64 * 256];   // 32 KB
  const int t = threadIdx.x;
  const int w = t >> 6, l = t & 63;
  const int lr = l & 15, lg = l >> 4;
  const int pblk = blockIdx.x * 64;
  const int z = blockIdx.z;
  const u16* Xb = Xbuf + (size_t)z * ((size_t)PP * CCH);

#pragma unroll
  for (int r = 0; r < 8; r++) {
    int G = r * 256 + t;
    int row = G >> 5, g = G & 31;
    int gs = (g & 24) | ((g & 7) ^ (row & 7));
    gload16(Xb + (size_t)(pblk + row) * CCH + gs * 8, (void*)&Xl[(size_t)G * 8]);
  }
  __syncthreads();

  f32x4 acc[4][4];
#pragma unroll
  for (int mi = 0; mi < 4; mi++)
#pragma unroll
    for (int ni = 0; ni < 4; ni++) acc[mi][ni] = (f32x4){0.f, 0.f, 0.f, 0.f};

#pragma unroll
  for (int kk = 0; kk < 4; kk++)
#pragma unroll
    for (int ks = 0; ks < 2; ks++) {
      const int q = kk * 8 + ks * 4 + lg;
      bf16x8 wf[4], xf[4];
#pragma unroll
      for (int i = 0; i < 4; i++) {
        size_t go = ((((size_t)(kk * 2 + ks) * 4 + w) * 4 + i) * 64 + l) * 8;
        wf[i] = *(const bf16x8*)(Wbf + go);
      }
#pragma unroll
      for (int i = 0; i < 4; i++) {
        int row = i * 16 + lr;
        int qp = (q & 24) | ((q & 7) ^ (row & 7));
        xf[i] = *(const bf16x8*)&Xl[row * 256 + qp * 8];
      }
#pragma unroll
      for (int mi = 0; mi < 4; mi++)
#pragma unroll
        for (int ni = 0; ni < 4; ni++)
          acc[mi][ni] = __builtin_amdgcn_mfma_f32_16x16x32_bf16(
              xf[mi], wf[ni], acc[mi][ni], 0, 0, 0);
    }

#pragma unroll
  for (int ni = 0; ni < 4; ni++) {
    int o = w * 64 + ni * 16 + lr;
    float bv = bias[o];
#pragma unroll
    for (int mi = 0; mi < 4; mi++) {
      int p = pblk + mi * 16 + lg * 4;
      f32x4 a = acc[mi][ni];
      float4 st = {a[0] + bv, a[1] + bv, a[2] + bv, a[3] + bv};
      *(float4*)(outY + ((size_t)z * CCH + o) * PP + p) = st;
    }
  }
}

// ---------------------------------------------------------------------------
// Attention, single-barrier (unchanged from R7 — ~14 us).
// ---------------------------------------------------------------------------
#define TX 32
#define TY 4
#define HX 34
#define HY 6
#define NHP (HX * HY)
#define NGR (NHP * 4)
#define ARND 4

__device__ __forceinline__ void fma8(const uint4 u, const float* qp, float& s) {
  s = fmaf(qp[0], bf2f(u.x & 0xffffu), s);
  s = fmaf(qp[1], bf2f(u.x >> 16), s);
  s = fmaf(qp[2], bf2f(u.y & 0xffffu), s);
  s = fmaf(qp[3], bf2f(u.y >> 16), s);
  s = fmaf(qp[4], bf2f(u.z & 0xffffu), s);
  s = fmaf(qp[5], bf2f(u.z >> 16), s);
  s = fmaf(qp[6], bf2f(u.w & 0xffffu), s);
  s = fmaf(qp[7], bf2f(u.w >> 16), s);
}
__device__ __forceinline__ void acc8(const uint4 u, float gv, float* op) {
  op[0] = fmaf(gv, bf2f(u.x & 0xffffu), op[0]);
  op[1] = fmaf(gv, bf2f(u.x >> 16), op[1]);
  op[2] = fmaf(gv, bf2f(u.y & 0xffffu), op[2]);
  op[3] = fmaf(gv, bf2f(u.y >> 16), op[3]);
  op[4] = fmaf(gv, bf2f(u.z & 0xffffu), op[4]);
  op[5] = fmaf(gv, bf2f(u.z >> 16), op[5]);
  op[6] = fmaf(gv, bf2f(u.w & 0xffffu), op[6]);
  op[7] = fmaf(gv, bf2f(u.w >> 16), op[7]);
}

__global__ __launch_bounds__(256)
void attn_1b(const u16* __restrict__ Kt, const u16* __restrict__ Vt,
             u16* __restrict__ Qt, const float* __restrict__ pe_dw,
             const float* __restrict__ pe_pw) {
  __shared__ __align__(16) u16 kl[NHP * 32];
  __shared__ __align__(16) u16 vl[NHP * 32];
  __shared__ float coef[81];
  const int t = threadIdx.x;
  if (t < 81) coef[t] = pe_pw[t] * pe_dw[t % 9];

  const int lx = t & 31;
  const int h2 = (t >> 5) & 1;
  const int ly = t >> 6;
  const int x0 = blockIdx.x * TX;
  const int y0 = blockIdx.y * TY;
  const int b = blockIdx.z >> 3;
  const int h = blockIdx.z & 7;
  const size_t nbase = (size_t)b * PP * CCH + h * CH;
  const int p = (y0 + ly) * WW + (x0 + lx);
  const size_t pixhalf = nbase + (size_t)p * CCH + h2 * 16;

  uint4 kg[ARND], vg[ARND];
#pragma unroll
  for (int r = 0; r < ARND; r++) {
    int s = t + r * 256;
    int pix = s >> 2, g = s & 3;
    int hy = pix / HX, hx = pix - hy * HX;
    int gx = x0 - 1 + hx, gy = y0 - 1 + hy;
    bool ok = (s < NGR) & (gx >= 0) & (gx < WW) & (gy >= 0) & (gy < HH);
    uint4 u = make_uint4(0u, 0u, 0u, 0u);
    if (ok) u = *(const uint4*)(Kt + nbase + (size_t)(gy * WW + gx) * CCH + g * 8);
    kg[r] = u;
  }
#pragma unroll
  for (int r = 0; r < ARND; r++) {
    int s = t + r * 256;
    int pix = s >> 2, g = s & 3;
    int hy = pix / HX, hx = pix - hy * HX;
    int gx = x0 - 1 + hx, gy = y0 - 1 + hy;
    bool ok = (s < NGR) & (gx >= 0) & (gx < WW) & (gy >= 0) & (gy < HH);
    uint4 u = make_uint4(0u, 0u, 0u, 0u);
    if (ok) u = *(const uint4*)(Vt + nbase + (size_t)(gy * WW + gx) * CCH + g * 8);
    vg[r] = u;
  }
  uint4 q0 = *(const uint4*)(Qt + pixhalf);
  uint4 q1 = *(const uint4*)(Qt + pixhalf + 8);

#pragma unroll
  for (int r = 0; r < ARND; r++) {
    int s = t + r * 256;
    if (s < NGR) {
      int pix = s >> 2, g = s & 3;
      *(uint4*)(&kl[pix * 32 + (((g + (pix >> 1)) & 3) << 3)]) = kg[r];
    }
  }
#pragma unroll
  for (int r = 0; r < ARND; r++) {
    int s = t + r * 256;
    if (s < NGR) {
      int pix = s >> 2, g = s & 3;
      *(uint4*)(&vl[pix * 32 + (((g + (pix >> 1)) & 3) << 3)]) = vg[r];
    }
  }
  __syncthreads();

  float qh[16];
  qh[0] = bf2f(q0.x & 0xffffu); qh[1] = bf2f(q0.x >> 16);
  qh[2] = bf2f(q0.y & 0xffffu); qh[3] = bf2f(q0.y >> 16);
  qh[4] = bf2f(q0.z & 0xffffu); qh[5] = bf2f(q0.z >> 16);
  qh[6] = bf2f(q0.w & 0xffffu); qh[7] = bf2f(q0.w >> 16);
  qh[8] = bf2f(q1.x & 0xffffu); qh[9] = bf2f(q1.x >> 16);
  qh[10] = bf2f(q1.y & 0xffffu); qh[11] = bf2f(q1.y >> 16);
  qh[12] = bf2f(q1.z & 0xffffu); qh[13] = bf2f(q1.z >> 16);
  qh[14] = bf2f(q1.w & 0xffffu); qh[15] = bf2f(q1.w >> 16);

  float f[9];
#pragma unroll
  for (int kk = 0; kk < 9; kk++) {
    int pix = (ly + kk / 3) * HX + lx + kk % 3;
    int ga = h2 * 2;
    uint4 ka = *(const uint4*)(&kl[pix * 32 + (((ga + (pix >> 1)) & 3) << 3)]);
    uint4 kb = *(const uint4*)(&kl[pix * 32 + (((ga + 1 + (pix >> 1)) & 3) << 3)]);
    float s = 0.f;
    fma8(ka, qh, s);
    fma8(kb, qh + 8, s);
    f[kk] = s + __shfl_xor(s, 32, 64);
  }

  float g[9], m = -1e30f;
#pragma unroll
  for (int k2 = 0; k2 < 9; k2++) {
    float s = 0.f;
#pragma unroll
    for (int kk = 0; kk < 9; kk++) s = fmaf(coef[k2 * 9 + kk], f[kk], s);
    g[k2] = s;
    m = fmaxf(m, s);
  }
  float ssum = 0.f;
#pragma unroll
  for (int k2 = 0; k2 < 9; k2++) {
    g[k2] = __expf(g[k2] - m);
    ssum += g[k2];
  }
  float inv = 1.f / ssum;
#pragma unroll
  for (int k2 = 0; k2 < 9; k2++) g[k2] *= inv;

  float oh[16];
#pragma unroll
  for (int j = 0; j < 16; j++) oh[j] = 0.f;
#pragma unroll
  for (int kk = 0; kk < 9; kk++) {
    int pix = (ly + kk / 3) * HX + lx + kk % 3;
    int ga = h2 * 2;
    uint4 va = *(const uint4*)(&vl[pix * 32 + (((ga + (pix >> 1)) & 3) << 3)]);
    uint4 vb = *(const uint4*)(&vl[pix * 32 + (((ga + 1 + (pix >> 1)) & 3) << 3)]);
    acc8(va, g[kk], oh);
    acc8(vb, g[kk], oh + 8);
  }
  uint4 s0, s1;
  s0.x = (unsigned)f2bf(oh[0]) | ((unsigned)f2bf(oh[1]) << 16);
  s0.y = (unsigned)f2bf(oh[2]) | ((unsigned)f2bf(oh[3]) << 16);
  s0.z = (unsigned)f2bf(oh[4]) | ((unsigned)f2bf(oh[5]) << 16);
  s0.w = (unsigned)f2bf(oh[6]) | ((unsigned)f2bf(oh[7]) << 16);
  s1.x = (unsigned)f2bf(oh[8]) | ((unsigned)f2bf(oh[9]) << 16);
  s1.y = (unsigned)f2bf(oh[10]) | ((unsigned)f2bf(oh[11]) << 16);
  s1.z = (unsigned)f2bf(oh[12]) | ((unsigned)f2bf(oh[13]) << 16);
  s1.w = (unsigned)f2bf(oh[14]) | ((unsigned)f2bf(oh[15]) << 16);
  *(uint4*)(Qt + pixhalf) = s0;
  *(uint4*)(Qt + pixhalf + 8) = s1;
}

// ---------------------------------------------------------------------------
extern "C" void kernel_launch(void* const* d_in, const int* in_sizes, int n_in,
                              void* d_out, int out_size, void* d_ws, size_t ws_size,
                              hipStream_t stream) {
  const float* q     = (const float*)d_in[0];
  const float* k     = (const float*)d_in[1];
  const float* v     = (const float*)d_in[2];
  const float* wq    = (const float*)d_in[3];
  const float* pe_dw = (const float*)d_in[4];
  const float* pe_pw = (const float*)d_in[5];
  const float* wo    = (const float*)d_in[6];
  const float* bo    = (const float*)d_in[7];
  float* out = (float*)d_out;

  const size_t seg = (size_t)BB * PP * CCH;
  u16* Xcl = (u16*)d_ws;                 // 3*seg bf16: q,k,v projections
  u16* Wbf = Xcl + 3 * seg;              // 131072 bf16: W2(wq) | W2(wo)

  wcvt<<<64, 256, 0, stream>>>(wq, wo, Wbf);

  gemm_qkvf<<<dim3(PP / BM, 1, 12), 1024, 0, stream>>>(q, k, v, Wbf, Xcl);

  u16* Qs = Xcl;
  u16* Ks = Xcl + seg;
  u16* Vs = Xcl + 2 * seg;
  attn_1b<<<dim3(WW / TX, HH / TY, BB * 8), 256, 0, stream>>>(Ks, Vs, Qs, pe_dw, pe_pw);

  gemm_out_m<<<dim3(PP / 64, 1, BB), 256, 0, stream>>>(Qs, Wbf + 65536, bo, out);
}

// Round 15
// 85.190 us; speedup vs baseline: 1.1726x; 1.1726x over previous
//
#include <hip/hip_runtime.h>
#include <math.h>

#define HH 96
#define WW 96
#define PP 9216   // H*W
#define CCH 256
#define BB 4
#define CH 32

typedef unsigned short u16;
typedef short bf16x8 __attribute__((ext_vector_type(8)));
typedef float f32x4 __attribute__((ext_vector_type(4)));

__device__ __forceinline__ float bf2f(unsigned s) { return __uint_as_float(s << 16); }
__device__ __forceinline__ u16 f2bf(float f) {
  unsigned u = __float_as_uint(f);
  return (u16)((u + 0x7fffu + ((u >> 16) & 1u)) >> 16);
}

typedef __attribute__((address_space(1))) const unsigned int GUI;
typedef __attribute__((address_space(3))) unsigned int LUI;
__device__ __forceinline__ void gload16(const void* g, void* l) {
  __builtin_amdgcn_global_load_lds((GUI*)g, (LUI*)l, 16, 0, 0);
}

// ---------------------------------------------------------------------------
// wcvt: W -> bf16 in per-lane FRAGMENT order (unchanged from R8-R13).
// ---------------------------------------------------------------------------
__global__ __launch_bounds__(256)
void wcvt(const float* __restrict__ wq, const float* __restrict__ wo,
          u16* __restrict__ Wbf) {
  int gidx = blockIdx.x * 256 + threadIdx.x;   // 0..16383
  int mat = gidx >> 13;
  int gi = gidx & 8191;
  int l = gi & 63;
  int i = (gi >> 6) & 3;
  int w = (gi >> 8) & 3;
  int ks = (gi >> 10) & 1;
  int kk = (gi >> 11) & 3;
  const float* W = mat ? wo : wq;
  int row = w * 64 + i * 16 + (l & 15);
  int c0 = kk * 64 + (ks * 4 + (l >> 4)) * 8;
  const float* s = W + (size_t)row * CCH + c0;
  float4 a = *(const float4*)s;
  float4 b = *(const float4*)(s + 4);
  uint4 u;
  u.x = (unsigned)f2bf(a.x) | ((unsigned)f2bf(a.y) << 16);
  u.y = (unsigned)f2bf(a.z) | ((unsigned)f2bf(a.w) << 16);
  u.z = (unsigned)f2bf(b.x) | ((unsigned)f2bf(b.y) << 16);
  u.w = (unsigned)f2bf(b.z) | ((unsigned)f2bf(b.w) << 16);
  *(uint4*)(Wbf + (size_t)gidx * 8) = u;
}

// ---------------------------------------------------------------------------
// Fused projection GEMM v6 + XCD-chunked swizzle (T1). Wave-private pipelined
// staging (counted vmcnt, no staging barriers), one barrier before MFMA.
// Grid flattened to 1D (1728 blocks, 1728%8==0): swz=(id&7)*216+(id>>3)
// gives each XCD a contiguous (z,pblk) run -> dense DRAM pages + no L2
// sector duplication on the read path (the measured ~2.8 TB/s wall).
// ---------------------------------------------------------------------------
#define XROW 264
__global__ __launch_bounds__(512)
void gemm_qkvf(const float* __restrict__ qin, const float* __restrict__ kin,
               const float* __restrict__ vin, const u16* __restrict__ Wbf,
               u16* __restrict__ Xcl) {
  __shared__ float fA[2][64 * 64];   // 2 x 16 KB f32 quarter [c_local][p]
  __shared__ u16 Xb[64 * XROW];      // 33 KB bf16 CL [p][c], padded rows
  const int t = threadIdx.x;
  const int w = t >> 6, l = t & 63;
  const int lr = l & 15, lg = l >> 4;

  // XCD-chunked bijective swizzle: 1728 blocks, 8 XCDs, 216 per chunk.
  const int id = blockIdx.x;
  const int swz = (id & 7) * 216 + (id >> 3);
  const int xb = swz % 144;
  const int z = swz / 144;
  const int pblk = xb * 64;
  const int b = z & 3, which = z >> 2;
  const float* Xf = ((which == 0) ? qin : (which == 1) ? kin : vin) + (size_t)b * CCH * PP;
  u16* Y = Xcl + (size_t)z * ((size_t)PP * CCH);

  auto stage = [&](int q, int buf) {
#pragma unroll
    for (int i = 0; i < 2; i++) {
      int inst = w * 2 + i;                  // 0..15
      int c = q * 64 + inst * 4 + (l >> 4);
      gload16(Xf + (size_t)c * PP + pblk + (l & 15) * 4,
              (void*)&fA[buf][inst * 256]);
    }
  };
  auto trans = [&](int q, int buf) {
    const float* src = &fA[buf][w * 8 * 64 + l];
    unsigned wds[4];
#pragma unroll
    for (int j = 0; j < 4; j++) {
      float e0 = src[(2 * j) * 64];
      float e1 = src[(2 * j + 1) * 64];
      wds[j] = (unsigned)f2bf(e0) | ((unsigned)f2bf(e1) << 16);
    }
    *(uint4*)(&Xb[l * XROW + (q * 8 + w) * 8]) =
        make_uint4(wds[0], wds[1], wds[2], wds[3]);
  };

  stage(0, 0);
  stage(1, 1);
  asm volatile("s_waitcnt vmcnt(2)" ::: "memory");   // quarter 0 landed
  __builtin_amdgcn_sched_barrier(0);
  trans(0, 0);
  stage(2, 0);                                       // overwrites MY rows only
  asm volatile("s_waitcnt vmcnt(2)" ::: "memory");   // quarter 1 landed
  __builtin_amdgcn_sched_barrier(0);
  trans(1, 1);
  stage(3, 1);
  asm volatile("s_waitcnt vmcnt(2)" ::: "memory");   // quarter 2 landed
  __builtin_amdgcn_sched_barrier(0);
  trans(2, 0);
  asm volatile("s_waitcnt vmcnt(0)" ::: "memory");   // quarter 3 landed
  __builtin_amdgcn_sched_barrier(0);
  trans(3, 1);
  __syncthreads();   // the ONE barrier: Xb visible to all waves

  f32x4 acc[2][4];
#pragma unroll
  for (int mi = 0; mi < 2; mi++)
#pragma unroll
    for (int ni = 0; ni < 4; ni++) acc[mi][ni] = (f32x4){0.f, 0.f, 0.f, 0.f};

#pragma unroll
  for (int kk = 0; kk < 4; kk++)
#pragma unroll
    for (int ks = 0; ks < 2; ks++) {
      const int qcol = kk * 8 + ks * 4 + lg;
      bf16x8 wf[2], xf[4];
#pragma unroll
      for (int mi = 0; mi < 2; mi++) {
        size_t go = ((((size_t)(kk * 2 + ks) * 4 + (w >> 1)) * 4 +
                      ((w & 1) * 2 + mi)) * 64 + l) * 8;
        wf[mi] = *(const bf16x8*)(Wbf + go);
      }
#pragma unroll
      for (int i = 0; i < 4; i++) {
        int row = i * 16 + lr;
        xf[i] = *(const bf16x8*)&Xb[row * XROW + qcol * 8];
      }
#pragma unroll
      for (int mi = 0; mi < 2; mi++)
#pragma unroll
        for (int ni = 0; ni < 4; ni++)
          acc[mi][ni] = __builtin_amdgcn_mfma_f32_16x16x32_bf16(
              wf[mi], xf[ni], acc[mi][ni], 0, 0, 0);
    }

#pragma unroll
  for (int mi = 0; mi < 2; mi++)
#pragma unroll
    for (int ni = 0; ni < 4; ni++) {
      int o = w * 32 + mi * 16 + lg * 4;
      int p = pblk + ni * 16 + lr;
      f32x4 a = acc[mi][ni];
      uint2 u;
      u.x = (unsigned)f2bf(a[0]) | ((unsigned)f2bf(a[1]) << 16);
      u.y = (unsigned)f2bf(a[2]) | ((unsigned)f2bf(a[3]) << 16);
      *(uint2*)(Y + (size_t)p * CCH + o) = u;
    }
}

// ---------------------------------------------------------------------------
// Out-projection GEMM (unchanged — measured at read floor).
// ---------------------------------------------------------------------------
__global__ __launch_bounds__(256)
void gemm_out_m(const u16* __restrict__ Xbuf, const u16* __restrict__ Wbf,
                const float* __restrict__ bias, float* __restrict__ outY) {
  __shared__ u16 Xl[64 * 256];   // 32 KB
  const int t = threadIdx.x;
  const int w = t >> 6, l = t & 63;
  const int lr = l & 15, lg = l >> 4;
  const int pblk = blockIdx.x * 64;
  const int z = blockIdx.z;
  const u16* Xb = Xbuf + (size_t)z * ((size_t)PP * CCH);

#pragma unroll
  for (int r = 0; r < 8; r++) {
    int G = r * 256 + t;
    int row = G >> 5, g = G & 31;
    int gs = (g & 24) | ((g & 7) ^ (row & 7));
    gload16(Xb + (size_t)(pblk + row) * CCH + gs * 8, (void*)&Xl[(size_t)G * 8]);
  }
  __syncthreads();

  f32x4 acc[4][4];
#pragma unroll
  for (int mi = 0; mi < 4; mi++)
#pragma unroll
    for (int ni = 0; ni < 4; ni++) acc[mi][ni] = (f32x4){0.f, 0.f, 0.f, 0.f};

#pragma unroll
  for (int kk = 0; kk < 4; kk++)
#pragma unroll
    for (int ks = 0; ks < 2; ks++) {
      const int q = kk * 8 + ks * 4 + lg;
      bf16x8 wf[4], xf[4];
#pragma unroll
      for (int i = 0; i < 4; i++) {
        size_t go = ((((size_t)(kk * 2 + ks) * 4 + w) * 4 + i) * 64 + l) * 8;
        wf[i] = *(const bf16x8*)(Wbf + go);
      }
#pragma unroll
      for (int i = 0; i < 4; i++) {
        int row = i * 16 + lr;
        int qp = (q & 24) | ((q & 7) ^ (row & 7));
        xf[i] = *(const bf16x8*)&Xl[row * 256 + qp * 8];
      }
#pragma unroll
      for (int mi = 0; mi < 4; mi++)
#pragma unroll
        for (int ni = 0; ni < 4; ni++)
          acc[mi][ni] = __builtin_amdgcn_mfma_f32_16x16x32_bf16(
              xf[mi], wf[ni], acc[mi][ni], 0, 0, 0);
    }

#pragma unroll
  for (int ni = 0; ni < 4; ni++) {
    int o = w * 64 + ni * 16 + lr;
    float bv = bias[o];
#pragma unroll
    for (int mi = 0; mi < 4; mi++) {
      int p = pblk + mi * 16 + lg * 4;
      f32x4 a = acc[mi][ni];
      float4 st = {a[0] + bv, a[1] + bv, a[2] + bv, a[3] + bv};
      *(float4*)(outY + ((size_t)z * CCH + o) * PP + p) = st;
    }
  }
}

// ---------------------------------------------------------------------------
// Attention, single-barrier (unchanged from R7 — at read floor, ~14 us).
// ---------------------------------------------------------------------------
#define TX 32
#define TY 4
#define HX 34
#define HY 6
#define NHP (HX * HY)
#define NGR (NHP * 4)
#define ARND 4

__device__ __forceinline__ void fma8(const uint4 u, const float* qp, float& s) {
  s = fmaf(qp[0], bf2f(u.x & 0xffffu), s);
  s = fmaf(qp[1], bf2f(u.x >> 16), s);
  s = fmaf(qp[2], bf2f(u.y & 0xffffu), s);
  s = fmaf(qp[3], bf2f(u.y >> 16), s);
  s = fmaf(qp[4], bf2f(u.z & 0xffffu), s);
  s = fmaf(qp[5], bf2f(u.z >> 16), s);
  s = fmaf(qp[6], bf2f(u.w & 0xffffu), s);
  s = fmaf(qp[7], bf2f(u.w >> 16), s);
}
__device__ __forceinline__ void acc8(const uint4 u, float gv, float* op) {
  op[0] = fmaf(gv, bf2f(u.x & 0xffffu), op[0]);
  op[1] = fmaf(gv, bf2f(u.x >> 16), op[1]);
  op[2] = fmaf(gv, bf2f(u.y & 0xffffu), op[2]);
  op[3] = fmaf(gv, bf2f(u.y >> 16), op[3]);
  op[4] = fmaf(gv, bf2f(u.z & 0xffffu), op[4]);
  op[5] = fmaf(gv, bf2f(u.z >> 16), op[5]);
  op[6] = fmaf(gv, bf2f(u.w & 0xffffu), op[6]);
  op[7] = fmaf(gv, bf2f(u.w >> 16), op[7]);
}

__global__ __launch_bounds__(256)
void attn_1b(const u16* __restrict__ Kt, const u16* __restrict__ Vt,
             u16* __restrict__ Qt, const float* __restrict__ pe_dw,
             const float* __restrict__ pe_pw) {
  __shared__ __align__(16) u16 kl[NHP * 32];
  __shared__ __align__(16) u16 vl[NHP * 32];
  __shared__ float coef[81];
  const int t = threadIdx.x;
  if (t < 81) coef[t] = pe_pw[t] * pe_dw[t % 9];

  const int lx = t & 31;
  const int h2 = (t >> 5) & 1;
  const int ly = t >> 6;
  const int x0 = blockIdx.x * TX;
  const int y0 = blockIdx.y * TY;
  const int b = blockIdx.z >> 3;
  const int h = blockIdx.z & 7;
  const size_t nbase = (size_t)b * PP * CCH + h * CH;
  const int p = (y0 + ly) * WW + (x0 + lx);
  const size_t pixhalf = nbase + (size_t)p * CCH + h2 * 16;

  uint4 kg[ARND], vg[ARND];
#pragma unroll
  for (int r = 0; r < ARND; r++) {
    int s = t + r * 256;
    int pix = s >> 2, g = s & 3;
    int hy = pix / HX, hx = pix - hy * HX;
    int gx = x0 - 1 + hx, gy = y0 - 1 + hy;
    bool ok = (s < NGR) & (gx >= 0) & (gx < WW) & (gy >= 0) & (gy < HH);
    uint4 u = make_uint4(0u, 0u, 0u, 0u);
    if (ok) u = *(const uint4*)(Kt + nbase + (size_t)(gy * WW + gx) * CCH + g * 8);
    kg[r] = u;
  }
#pragma unroll
  for (int r = 0; r < ARND; r++) {
    int s = t + r * 256;
    int pix = s >> 2, g = s & 3;
    int hy = pix / HX, hx = pix - hy * HX;
    int gx = x0 - 1 + hx, gy = y0 - 1 + hy;
    bool ok = (s < NGR) & (gx >= 0) & (gx < WW) & (gy >= 0) & (gy < HH);
    uint4 u = make_uint4(0u, 0u, 0u, 0u);
    if (ok) u = *(const uint4*)(Vt + nbase + (size_t)(gy * WW + gx) * CCH + g * 8);
    vg[r] = u;
  }
  uint4 q0 = *(const uint4*)(Qt + pixhalf);
  uint4 q1 = *(const uint4*)(Qt + pixhalf + 8);

#pragma unroll
  for (int r = 0; r < ARND; r++) {
    int s = t + r * 256;
    if (s < NGR) {
      int pix = s >> 2, g = s & 3;
      *(uint4*)(&kl[pix * 32 + (((g + (pix >> 1)) & 3) << 3)]) = kg[r];
    }
  }
#pragma unroll
  for (int r = 0; r < ARND; r++) {
    int s = t + r * 256;
    if (s < NGR) {
      int pix = s >> 2, g = s & 3;
      *(uint4*)(&vl[pix * 32 + (((g + (pix >> 1)) & 3) << 3)]) = vg[r];
    }
  }
  __syncthreads();

  float qh[16];
  qh[0] = bf2f(q0.x & 0xffffu); qh[1] = bf2f(q0.x >> 16);
  qh[2] = bf2f(q0.y & 0xffffu); qh[3] = bf2f(q0.y >> 16);
  qh[4] = bf2f(q0.z & 0xffffu); qh[5] = bf2f(q0.z >> 16);
  qh[6] = bf2f(q0.w & 0xffffu); qh[7] = bf2f(q0.w >> 16);
  qh[8] = bf2f(q1.x & 0xffffu); qh[9] = bf2f(q1.x >> 16);
  qh[10] = bf2f(q1.y & 0xffffu); qh[11] = bf2f(q1.y >> 16);
  qh[12] = bf2f(q1.z & 0xffffu); qh[13] = bf2f(q1.z >> 16);
  qh[14] = bf2f(q1.w & 0xffffu); qh[15] = bf2f(q1.w >> 16);

  float f[9];
#pragma unroll
  for (int kk = 0; kk < 9; kk++) {
    int pix = (ly + kk / 3) * HX + lx + kk % 3;
    int ga = h2 * 2;
    uint4 ka = *(const uint4*)(&kl[pix * 32 + (((ga + (pix >> 1)) & 3) << 3)]);
    uint4 kb = *(const uint4*)(&kl[pix * 32 + (((ga + 1 + (pix >> 1)) & 3) << 3)]);
    float s = 0.f;
    fma8(ka, qh, s);
    fma8(kb, qh + 8, s);
    f[kk] = s + __shfl_xor(s, 32, 64);
  }

  float g[9], m = -1e30f;
#pragma unroll
  for (int k2 = 0; k2 < 9; k2++) {
    float s = 0.f;
#pragma unroll
    for (int kk = 0; kk < 9; kk++) s = fmaf(coef[k2 * 9 + kk], f[kk], s);
    g[k2] = s;
    m = fmaxf(m, s);
  }
  float ssum = 0.f;
#pragma unroll
  for (int k2 = 0; k2 < 9; k2++) {
    g[k2] = __expf(g[k2] - m);
    ssum += g[k2];
  }
  float inv = 1.f / ssum;
#pragma unroll
  for (int k2 = 0; k2 < 9; k2++) g[k2] *= inv;

  float oh[16];
#pragma unroll
  for (int j = 0; j < 16; j++) oh[j] = 0.f;
#pragma unroll
  for (int kk = 0; kk < 9; kk++) {
    int pix = (ly + kk / 3) * HX + lx + kk % 3;
    int ga = h2 * 2;
    uint4 va = *(const uint4*)(&vl[pix * 32 + (((ga + (pix >> 1)) & 3) << 3)]);
    uint4 vb = *(const uint4*)(&vl[pix * 32 + (((ga + 1 + (pix >> 1)) & 3) << 3)]);
    acc8(va, g[kk], oh);
    acc8(vb, g[kk], oh + 8);
  }
  uint4 s0, s1;
  s0.x = (unsigned)f2bf(oh[0]) | ((unsigned)f2bf(oh[1]) << 16);
  s0.y = (unsigned)f2bf(oh[2]) | ((unsigned)f2bf(oh[3]) << 16);
  s0.z = (unsigned)f2bf(oh[4]) | ((unsigned)f2bf(oh[5]) << 16);
  s0.w = (unsigned)f2bf(oh[6]) | ((unsigned)f2bf(oh[7]) << 16);
  s1.x = (unsigned)f2bf(oh[8]) | ((unsigned)f2bf(oh[9]) << 16);
  s1.y = (unsigned)f2bf(oh[10]) | ((unsigned)f2bf(oh[11]) << 16);
  s1.z = (unsigned)f2bf(oh[12]) | ((unsigned)f2bf(oh[13]) << 16);
  s1.w = (unsigned)f2bf(oh[14]) | ((unsigned)f2bf(oh[15]) << 16);
  *(uint4*)(Qt + pixhalf) = s0;
  *(uint4*)(Qt + pixhalf + 8) = s1;
}

// ---------------------------------------------------------------------------
extern "C" void kernel_launch(void* const* d_in, const int* in_sizes, int n_in,
                              void* d_out, int out_size, void* d_ws, size_t ws_size,
                              hipStream_t stream) {
  const float* q     = (const float*)d_in[0];
  const float* k     = (const float*)d_in[1];
  const float* v     = (const float*)d_in[2];
  const float* wq    = (const float*)d_in[3];
  const float* pe_dw = (const float*)d_in[4];
  const float* pe_pw = (const float*)d_in[5];
  const float* wo    = (const float*)d_in[6];
  const float* bo    = (const float*)d_in[7];
  float* out = (float*)d_out;

  const size_t seg = (size_t)BB * PP * CCH;
  u16* Xcl = (u16*)d_ws;                 // 3*seg bf16: q,k,v projections
  u16* Wbf = Xcl + 3 * seg;              // 131072 bf16: W2(wq) | W2(wo)

  wcvt<<<64, 256, 0, stream>>>(wq, wo, Wbf);

  // 1D grid, XCD-chunk-swizzled inside (144 pblk x 12 z = 1728 blocks)
  gemm_qkvf<<<dim3(144 * 12, 1, 1), 512, 0, stream>>>(q, k, v, Wbf, Xcl);

  u16* Qs = Xcl;
  u16* Ks = Xcl + seg;
  u16* Vs = Xcl + 2 * seg;
  attn_1b<<<dim3(WW / TX, HH / TY, BB * 8), 256, 0, stream>>>(Ks, Vs, Qs, pe_dw, pe_pw);

  gemm_out_m<<<dim3(PP / 64, 1, BB), 256, 0, stream>>>(Qs, Wbf + 65536, bo, out);
}